// Round 7
// baseline (283.351 us; speedup 1.0000x reference)
//
#include <hip/hip_runtime.h>
#include <math.h>

// Problem constants (fixed by reference)
#define B_TOT   256
#define N_TOT   2304
#define IN_DIM  8
#define NC      10      // NUM_CLASSES
#define OD      16      // OUT_DIM
#define CD      160     // NC*OD
#define RBIAS   0.1f

// R3's proven geometry: 512 blocks = 2/CU, CU-paired on same n-range.
#define BTILE    64                      // b per block (= wave lanes)
#define NS       128                     // n-slices
#define NPB      (N_TOT / NS)            // 18 n per block
#define NTHREADS 640                     // 10 waves
#define XR       (NPB * IN_DIM + 4)      // 148: x row stride
#define LB       72                      // logit board row stride
#define NF4      (B_TOT * CD / 4)        // 10240 float4 per partial slab
#define WROW     (IN_DIM * CD)           // 1280 floats per W row
#define WUP      640                     // upper-half W slice: 8i*10c*8d floats

#define NXCD     8

// Reduce: 1280 blocks × 256 thr = 5 blk/CU balanced
#define RCOLS    8
#define RGRPS    32
#define RYPER    (NS / RGRPS)            // 4

// async global->LDS, 16B per lane; LDS dst = wave-uniform base + lane*16 (HW)
#define GLDS16(gp, lp) __builtin_amdgcn_global_load_lds(                 \
    (const __attribute__((address_space(1))) void*)(gp),                  \
    (__attribute__((address_space(3))) void*)(lp), 16, 0, 0)

// ===== Routing round, R7: HYBRID W delivery (split across two pipes).
// Measured path costs per CU-nn (R1-R6): scalar-only 6.6Kcy (chain/serial
// wall), LDS-broadcast-only 8.4Kcy (b128 = 12.4cy even when broadcast),
// readlane +128 VALU ops. Split: d0..7 via scalar K$ (64 floats -> 8
// INDEPENDENT s_load_dwordx8, chain depth 1, fits SGPR budget), d8..15 via
// global_load_lds dbuf + broadcast ds_read_b128 (16/wave-nn = 4.0Kcy/CU-nn
// on the LDS pipe, parallel to scalar ~3.3K and VALU ~3.3K).
// FMA order/values identical to R3 -> bit-identical output.
template <int FIRST>
__global__ __launch_bounds__(NTHREADS, 5) void routing_round(
    const float* __restrict__ x,      // [B, N, 8]
    const float* __restrict__ W,      // [N, 8, 160]
    const float* __restrict__ S_acc,  // [B, 160]
    float* __restrict__ part)         // [NS, B, 160]
{
    __shared__ __align__(16) float sh_x[BTILE * XR];   // 37.9 KB
    __shared__ __align__(16) float sh_w[2][WUP];       // 5.0 KB dbuf (d>=8)
    __shared__ float sh_lg[2][NC * LB];                // 5.8 KB
    // total 48.7 KB -> 2 blocks/CU (97.4 < 160 KB)

    const int tid = threadIdx.x;

    // R3's CU-pair map: xcd = o&7 (XCD round-robin, confirmed R1); ranks r
    // and r+32 co-reside -> same (y, n-range), different b0: W lines shared.
    const int o      = blockIdx.x;                 // 0..511
    const int xcd    = o & (NXCD - 1);
    const int r      = o >> 3;                     // 0..63
    const int cuslot = r & 31;
    const int pairid = r >> 5;
    const int ySlab  = xcd * 16 + (cuslot & 15);   // 0..127
    const int b0     = ((cuslot >> 4) * 2 + pairid) * BTILE;
    const int n0     = ySlab * NPB;

    const int b   = tid & 63;
    const int cu  = __builtin_amdgcn_readfirstlane(tid >> 6);

    // Staging map (160 lanes = 2560B of upper-half W per n):
    // lane L holds chunk (i = L/20, c = (L%20)>>1, h = L%2): 16B at
    // W[n, i, c*16 + 8 + 4h]. LDS dst linear: sh_w[buf] + L*4 floats;
    // per-wave uniform base cu*256 + HW lane*16B. Readback for (i,c):
    // 8 contiguous floats at 80*i + 8*c (one float4 pair).
    const int L = tid;
    int off_s = 0;
    if (L < 160) {
        const int i_s = L / 20;
        const int rem = L - i_s * 20;
        off_s = i_s * CD + (rem >> 1) * OD + 8 + (rem & 1) * 4;
    }

    // stage row-0 upper halves
    if (L < 160)
        GLDS16(W + (size_t)n0 * WROW + off_s, &sh_w[0][cu * 256]);

    // ---- stage x tile: [64 b][144 floats], coalesced float4
    {
        const int XT4 = BTILE * (NPB * IN_DIM / 4);   // 2304
        for (int k = tid; k < XT4; k += NTHREADS) {
            int bb   = k / (NPB * 2);
            int off4 = k - bb * (NPB * 2);
            float4 v = *(const float4*)(x + ((size_t)(b0 + bb) * N_TOT + n0) * IN_DIM + off4 * 4);
            *(float4*)(&sh_x[bb * XR + off4 * 4]) = v;
        }
    }

    // ---- S fragment: all 16 d for (b, c)
    float S[OD];
    if (!FIRST) {
        const float4* sp = (const float4*)(S_acc + (size_t)(b0 + b) * CD + cu * OD);
        #pragma unroll
        for (int q = 0; q < 4; q++) ((float4*)S)[q] = sp[q];
    }

    float acc[OD];
    #pragma unroll
    for (int d = 0; d < OD; d++) acc[d] = 0.f;

    asm volatile("s_waitcnt vmcnt(0)" ::: "memory");   // W row0 + x staged
    __syncthreads();

    const float* Wc = W + cu * OD;    // wave-uniform base -> scalar loads (d<8)

    for (int nn = 0; nn < NPB; nn++) {
        const int curw = nn & 1;

        // prefetch next row's upper halves into the other buffer
        if (L < 160 && nn + 1 < NPB)
            GLDS16(W + (size_t)(n0 + nn + 1) * WROW + off_s,
                   &sh_w[curw ^ 1][cu * 256]);

        float xf[IN_DIM];
        {
            const float4* xp = (const float4*)(&sh_x[b * XR + nn * IN_DIM]);
            ((float4*)xf)[0] = xp[0];
            ((float4*)xf)[1] = xp[1];
        }

        // u = x . W : d0..7 from scalar path (8 independent s_load_dwordx8),
        //             d8..15 from LDS broadcast frags (2 b128 per i).
        const float* Wn = Wc + (size_t)(n0 + nn) * WROW;
        const float* wu = &sh_w[curw][cu * 8];
        float u[OD];
        #pragma unroll
        for (int d = 0; d < OD; d++) u[d] = 0.f;
        #pragma unroll
        for (int i = 0; i < IN_DIM; i++) {
            const float* Wi = Wn + i * CD;                    // d 0..7 (SGPR)
            const float4* up = (const float4*)(wu + i * 80);  // d 8..15 (LDS)
            const float4 ua = up[0], ub = up[1];
            const float xi = xf[i];
            u[0]  = fmaf(xi, Wi[0], u[0]);
            u[1]  = fmaf(xi, Wi[1], u[1]);
            u[2]  = fmaf(xi, Wi[2], u[2]);
            u[3]  = fmaf(xi, Wi[3], u[3]);
            u[4]  = fmaf(xi, Wi[4], u[4]);
            u[5]  = fmaf(xi, Wi[5], u[5]);
            u[6]  = fmaf(xi, Wi[6], u[6]);
            u[7]  = fmaf(xi, Wi[7], u[7]);
            u[8]  = fmaf(xi, ua.x,  u[8]);
            u[9]  = fmaf(xi, ua.y,  u[9]);
            u[10] = fmaf(xi, ua.z,  u[10]);
            u[11] = fmaf(xi, ua.w,  u[11]);
            u[12] = fmaf(xi, ub.x,  u[12]);
            u[13] = fmaf(xi, ub.y,  u[13]);
            u[14] = fmaf(xi, ub.z,  u[14]);
            u[15] = fmaf(xi, ub.w,  u[15]);
        }

        if (!FIRST) {
            float lg = 0.f;
            #pragma unroll
            for (int d = 0; d < OD; d++) lg = fmaf(u[d], S[d], lg);
            sh_lg[curw][cu * LB + b] = lg;
            // single barrier per nn: publishes logit board AND next W buffer
            asm volatile("s_waitcnt vmcnt(0)" ::: "memory");
            __syncthreads();

            float m = -1e30f;
            float row[NC];
            #pragma unroll
            for (int k = 0; k < NC; k++) {
                row[k] = sh_lg[curw][k * LB + b];
                m = fmaxf(m, row[k]);
            }
            float den = 0.f;
            #pragma unroll
            for (int k = 0; k < NC; k++) den += __expf(row[k] - m);
            float cw = __expf(lg - m) / den;

            #pragma unroll
            for (int d = 0; d < OD; d++) acc[d] = fmaf(cw, u[d], acc[d]);
        } else {
            #pragma unroll
            for (int d = 0; d < OD; d++) acc[d] += u[d];
            if (nn + 1 < NPB) {
                asm volatile("s_waitcnt vmcnt(0)" ::: "memory");
                __syncthreads();   // next W buffer ready; cur fully consumed
            }
        }
    }

    float* dst = part + ((size_t)ySlab * B_TOT + (b0 + b)) * CD + cu * OD;
    #pragma unroll
    for (int q = 0; q < 4; q++)
        ((float4*)dst)[q] = ((float4*)acc)[q];
}

// ===== Full-device merged reduce: 1280 blocks × 256 threads = 5 blk/CU.
// Block owns 8 float4-columns; thread (col, grp) sums 4 slabs (y = grp+32k);
// LDS combine; threads 0..7 apply scale/bias + stage B:
// store S_acc (round 0 — no memset), add (round 1), squash -> v_out (round 2).
__global__ __launch_bounds__(256) void reduce_round(
    const float* __restrict__ part,   // [NS, B, 160]
    float* __restrict__ S_acc,        // [B, 160]
    float* __restrict__ v_out,        // [B, 10, 16]
    float scale, int round)
{
    __shared__ float4 sh[RGRPS][RCOLS];   // 4 KB

    const int col = threadIdx.x & (RCOLS - 1);
    const int grp = threadIdx.x >> 3;               // 0..31
    const int g   = blockIdx.x * RCOLS + col;       // float4 column index

    const float4* p4 = (const float4*)part + (size_t)grp * NF4 + g;
    float4 s = { 0.f, 0.f, 0.f, 0.f };
    #pragma unroll
    for (int y = 0; y < RYPER; y++) {               // slabs grp, grp+32, ...
        float4 t = p4[(size_t)y * RGRPS * NF4];
        s.x += t.x; s.y += t.y; s.z += t.z; s.w += t.w;
    }
    sh[grp][col] = s;
    __syncthreads();

    if (threadIdx.x < RCOLS) {
        float4 t = { 0.f, 0.f, 0.f, 0.f };
        #pragma unroll
        for (int k = 0; k < RGRPS; k++) {
            float4 q = sh[k][col];
            t.x += q.x; t.y += q.y; t.z += q.z; t.w += q.w;
        }
        t.x = t.x * scale + RBIAS;
        t.y = t.y * scale + RBIAS;
        t.z = t.z * scale + RBIAS;
        t.w = t.w * scale + RBIAS;

        if (round == 0) {
            ((float4*)S_acc)[g] = t;          // store — no memset required
        } else if (round == 1) {
            float4 o = ((float4*)S_acc)[g];
            o.x += t.x; o.y += t.y; o.z += t.z; o.w += t.w;
            ((float4*)S_acc)[g] = o;
        } else {
            // squash: 16 d = 4 consecutive float4 columns = lanes 4k..4k+3
            float ss = t.x * t.x + t.y * t.y + t.z * t.z + t.w * t.w;
            ss += __shfl_xor(ss, 1, 64);
            ss += __shfl_xor(ss, 2, 64);
            float norm = sqrtf(ss);
            float k2 = norm / (1.0f + ss);
            float4 v = { t.x * k2, t.y * k2, t.z * k2, t.w * k2 };
            ((float4*)v_out)[g] = v;
        }
    }
}

extern "C" void kernel_launch(void* const* d_in, const int* in_sizes, int n_in,
                              void* d_out, int out_size, void* d_ws, size_t ws_size,
                              hipStream_t stream) {
    const float* x = (const float*)d_in[0];   // [256,2304,8]
    const float* W = (const float*)d_in[1];   // [2304,8,160]
    float* out = (float*)d_out;               // [256,10,16]

    // Workspace (every byte written before read each call — re-poison safe)
    float* part  = (float*)d_ws;                            // NS * 40960  (~21 MB)
    float* S_acc = part + (size_t)NS * B_TOT * CD;          // 40960 floats

    const dim3 rgrid(NS * (B_TOT / BTILE));   // 512 blocks = 2/CU paired
    const int  RG = NF4 / RCOLS;              // 1280 reduce blocks — 5/CU

    // Round 0 (uniform cw; 0.1 folded into reduce scale; S_acc stored not added)
    routing_round<1><<<rgrid, NTHREADS, 0, stream>>>(x, W, S_acc, part);
    reduce_round<<<RG, 256, 0, stream>>>(part, S_acc, out, 0.1f, 0);

    // Round 1
    routing_round<0><<<rgrid, NTHREADS, 0, stream>>>(x, W, S_acc, part);
    reduce_round<<<RG, 256, 0, stream>>>(part, S_acc, out, 1.0f, 1);

    // Round 2 (+final squash fused)
    routing_round<0><<<rgrid, NTHREADS, 0, stream>>>(x, W, S_acc, part);
    reduce_round<<<RG, 256, 0, stream>>>(part, S_acc, out, 1.0f, 2);
}

// Round 8
// 212.312 us; speedup vs baseline: 1.3346x; 1.3346x over previous
//
#include <hip/hip_runtime.h>
#include <math.h>

// Problem constants (fixed by reference)
#define B_TOT   256
#define N_TOT   2304
#define IN_DIM  8
#define NC      10      // NUM_CLASSES
#define OD      16      // OUT_DIM
#define CD      160     // NC*OD
#define RBIAS   0.1f

// R8 geometry: Mr=2 (each lane owns TWO b rows) -> btile=128, grid=256
// (1 block/CU). Scalar-W bytes per FMA halve: 180 wave-nn/CU-round instead
// of 360. W mechanics identical to R3 (wave-uniform class slice -> s_load).
#define BTILE    128                     // b per block (2 per lane)
#define NS       128                     // n-slices
#define NPB      (N_TOT / NS)            // 18 n per block
#define NTHREADS 640                     // 10 waves
#define XR       (NPB * IN_DIM + 4)      // 148: x row stride
#define LB2      136                     // logit board row stride (128+8 pad)
#define NF4      (B_TOT * CD / 4)        // 10240 float4 per partial slab
#define WROW     (IN_DIM * CD)           // 1280 floats per W row

#define NXCD     8

// Reduce: unchanged from R3's proven config
#define RCOLS    8
#define RGRPS    32
#define RYPER    (NS / RGRPS)            // 4

// ===== Routing round, R8: Mr=2 scalar-W amortization.
// Transport ledger (measured R1-R7, per block-nn): scalar 3.3Kcy,
// LDS-broadcast 4.0Kcy (b128 reg-write-bound even when broadcast),
// readlane +128 VALU, hybrid worse (SGPR collapse). Scalar is best and
// is STREAMING (fresh K$ miss per nn; locality can't help - R1 proved).
// Only lever: more FMAs per scalar byte -> each lane computes b AND b+64
// with the same Wi chunk. Per CU-round scalar: 360 -> 180 wave-nn.
template <int FIRST>
__global__ __launch_bounds__(NTHREADS) void routing_round(
    const float* __restrict__ x,      // [B, N, 8]
    const float* __restrict__ W,      // [N, 8, 160]
    const float* __restrict__ S_acc,  // [B, 160]
    float* __restrict__ part)         // [NS, B, 160]
{
    __shared__ float sh_x[BTILE * XR];            // 75.8 KB
    __shared__ float sh_lg[2][NC * LB2];          // 10.9 KB
    // total 86.7 KB -> 1 block/CU; grid 256 = exactly 1 per CU

    const int tid = threadIdx.x;

    // XCD swizzle: xcd = bid&7 (confirmed R1); each XCD owns 16 contiguous
    // y-slices x 2 b-halves -> W n-range per XCD stays L2-local.
    const int bid   = blockIdx.x;                  // 0..255
    const int xcd   = bid & (NXCD - 1);
    const int slot  = bid >> 3;                    // 0..31
    const int ySlab = xcd * 16 + (slot & 15);      // 0..127
    const int b0    = (slot >> 4) * BTILE;         // 0 or 128
    const int n0    = ySlab * NPB;

    const int b   = tid & 63;
    const int cu  = __builtin_amdgcn_readfirstlane(tid >> 6);

    // ---- stage x tile: [128 b][144 floats], coalesced float4
    {
        const int XT4 = BTILE * (NPB * IN_DIM / 4);   // 4608
        for (int k = tid; k < XT4; k += NTHREADS) {
            int bb   = k / (NPB * 2);
            int off4 = k - bb * (NPB * 2);
            float4 v = *(const float4*)(x + ((size_t)(b0 + bb) * N_TOT + n0) * IN_DIM + off4 * 4);
            *(float4*)(&sh_x[bb * XR + off4 * 4]) = v;
        }
    }

    // ---- S fragments for both owned b rows
    float S0[OD], S1[OD];
    if (!FIRST) {
        const float4* sp0 = (const float4*)(S_acc + (size_t)(b0 + b) * CD + cu * OD);
        const float4* sp1 = (const float4*)(S_acc + (size_t)(b0 + 64 + b) * CD + cu * OD);
        #pragma unroll
        for (int q = 0; q < 4; q++) ((float4*)S0)[q] = sp0[q];
        #pragma unroll
        for (int q = 0; q < 4; q++) ((float4*)S1)[q] = sp1[q];
    }

    float acc0[OD], acc1[OD];
    #pragma unroll
    for (int d = 0; d < OD; d++) { acc0[d] = 0.f; acc1[d] = 0.f; }

    __syncthreads();   // sh_x ready

    const float* Wc = W + cu * OD;    // wave-uniform base -> scalar loads

    for (int nn = 0; nn < NPB; nn++) {
        float xf0[IN_DIM], xf1[IN_DIM];
        {
            const float4* xp0 = (const float4*)(&sh_x[b * XR + nn * IN_DIM]);
            const float4* xp1 = (const float4*)(&sh_x[(64 + b) * XR + nn * IN_DIM]);
            ((float4*)xf0)[0] = xp0[0];
            ((float4*)xf0)[1] = xp0[1];
            ((float4*)xf1)[0] = xp1[0];
            ((float4*)xf1)[1] = xp1[1];
        }

        // u = x . W for BOTH b rows from the SAME scalar Wi chunk.
        const float* Wn = Wc + (size_t)(n0 + nn) * WROW;
        float u0[OD], u1[OD];
        #pragma unroll
        for (int d = 0; d < OD; d++) { u0[d] = 0.f; u1[d] = 0.f; }
        #pragma unroll
        for (int i = 0; i < IN_DIM; i++) {
            const float* Wi = Wn + i * CD;
            const float xi0 = xf0[i], xi1 = xf1[i];
            #pragma unroll
            for (int d = 0; d < OD; d++) {
                const float w = Wi[d];
                u0[d] = fmaf(xi0, w, u0[d]);
                u1[d] = fmaf(xi1, w, u1[d]);
            }
        }

        if (!FIRST) {
            const int cur = nn & 1;
            float lg0 = 0.f, lg1 = 0.f;
            #pragma unroll
            for (int d = 0; d < OD; d++) {
                lg0 = fmaf(u0[d], S0[d], lg0);
                lg1 = fmaf(u1[d], S1[d], lg1);
            }
            sh_lg[cur][cu * LB2 + b]      = lg0;
            sh_lg[cur][cu * LB2 + 64 + b] = lg1;
            __syncthreads();   // board published (dbuf -> one barrier/nn)

            float m0 = -1e30f, m1 = -1e30f;
            float row0[NC], row1[NC];
            #pragma unroll
            for (int k = 0; k < NC; k++) {
                row0[k] = sh_lg[cur][k * LB2 + b];
                row1[k] = sh_lg[cur][k * LB2 + 64 + b];
                m0 = fmaxf(m0, row0[k]);
                m1 = fmaxf(m1, row1[k]);
            }
            float den0 = 0.f, den1 = 0.f;
            #pragma unroll
            for (int k = 0; k < NC; k++) {
                den0 += __expf(row0[k] - m0);
                den1 += __expf(row1[k] - m1);
            }
            const float cw0 = __expf(lg0 - m0) / den0;
            const float cw1 = __expf(lg1 - m1) / den1;

            #pragma unroll
            for (int d = 0; d < OD; d++) {
                acc0[d] = fmaf(cw0, u0[d], acc0[d]);
                acc1[d] = fmaf(cw1, u1[d], acc1[d]);
            }
        } else {
            #pragma unroll
            for (int d = 0; d < OD; d++) {
                acc0[d] += u0[d];
                acc1[d] += u1[d];
            }
            // round 0: no barriers in the loop at all (waves free-run ->
            // scalar pipe sees staggered demand, best overlap)
        }
    }

    float* dst0 = part + ((size_t)ySlab * B_TOT + (b0 + b)) * CD + cu * OD;
    float* dst1 = part + ((size_t)ySlab * B_TOT + (b0 + 64 + b)) * CD + cu * OD;
    #pragma unroll
    for (int q = 0; q < 4; q++) ((float4*)dst0)[q] = ((float4*)acc0)[q];
    #pragma unroll
    for (int q = 0; q < 4; q++) ((float4*)dst1)[q] = ((float4*)acc1)[q];
}

// ===== Full-device merged reduce: 1280 blocks × 256 threads = 5 blk/CU.
// Block owns 8 float4-columns; thread (col, grp) sums 4 slabs (y = grp+32k);
// LDS combine; threads 0..7 apply scale/bias + stage B:
// store S_acc (round 0 — no memset), add (round 1), squash -> v_out (round 2).
__global__ __launch_bounds__(256) void reduce_round(
    const float* __restrict__ part,   // [NS, B, 160]
    float* __restrict__ S_acc,        // [B, 160]
    float* __restrict__ v_out,        // [B, 10, 16]
    float scale, int round)
{
    __shared__ float4 sh[RGRPS][RCOLS];   // 4 KB

    const int col = threadIdx.x & (RCOLS - 1);
    const int grp = threadIdx.x >> 3;               // 0..31
    const int g   = blockIdx.x * RCOLS + col;       // float4 column index

    const float4* p4 = (const float4*)part + (size_t)grp * NF4 + g;
    float4 s = { 0.f, 0.f, 0.f, 0.f };
    #pragma unroll
    for (int y = 0; y < RYPER; y++) {               // slabs grp, grp+32, ...
        float4 t = p4[(size_t)y * RGRPS * NF4];
        s.x += t.x; s.y += t.y; s.z += t.z; s.w += t.w;
    }
    sh[grp][col] = s;
    __syncthreads();

    if (threadIdx.x < RCOLS) {
        float4 t = { 0.f, 0.f, 0.f, 0.f };
        #pragma unroll
        for (int k = 0; k < RGRPS; k++) {
            float4 q = sh[k][col];
            t.x += q.x; t.y += q.y; t.z += q.z; t.w += q.w;
        }
        t.x = t.x * scale + RBIAS;
        t.y = t.y * scale + RBIAS;
        t.z = t.z * scale + RBIAS;
        t.w = t.w * scale + RBIAS;

        if (round == 0) {
            ((float4*)S_acc)[g] = t;          // store — no memset required
        } else if (round == 1) {
            float4 o = ((float4*)S_acc)[g];
            o.x += t.x; o.y += t.y; o.z += t.z; o.w += t.w;
            ((float4*)S_acc)[g] = o;
        } else {
            // squash: 16 d = 4 consecutive float4 columns = lanes 4k..4k+3
            float ss = t.x * t.x + t.y * t.y + t.z * t.z + t.w * t.w;
            ss += __shfl_xor(ss, 1, 64);
            ss += __shfl_xor(ss, 2, 64);
            float norm = sqrtf(ss);
            float k2 = norm / (1.0f + ss);
            float4 v = { t.x * k2, t.y * k2, t.z * k2, t.w * k2 };
            ((float4*)v_out)[g] = v;
        }
    }
}

extern "C" void kernel_launch(void* const* d_in, const int* in_sizes, int n_in,
                              void* d_out, int out_size, void* d_ws, size_t ws_size,
                              hipStream_t stream) {
    const float* x = (const float*)d_in[0];   // [256,2304,8]
    const float* W = (const float*)d_in[1];   // [2304,8,160]
    float* out = (float*)d_out;               // [256,10,16]

    // Workspace (every byte written before read each call — re-poison safe)
    float* part  = (float*)d_ws;                            // NS * 40960  (~21 MB)
    float* S_acc = part + (size_t)NS * B_TOT * CD;          // 40960 floats

    const dim3 rgrid(NS * (B_TOT / BTILE));   // 256 blocks = 1/CU
    const int  RG = NF4 / RCOLS;              // 1280 reduce blocks — 5/CU

    // Round 0 (uniform cw; 0.1 folded into reduce scale; S_acc stored not added)
    routing_round<1><<<rgrid, NTHREADS, 0, stream>>>(x, W, S_acc, part);
    reduce_round<<<RG, 256, 0, stream>>>(part, S_acc, out, 0.1f, 0);

    // Round 1
    routing_round<0><<<rgrid, NTHREADS, 0, stream>>>(x, W, S_acc, part);
    reduce_round<<<RG, 256, 0, stream>>>(part, S_acc, out, 1.0f, 1);

    // Round 2 (+final squash fused)
    routing_round<0><<<rgrid, NTHREADS, 0, stream>>>(x, W, S_acc, part);
    reduce_round<<<RG, 256, 0, stream>>>(part, S_acc, out, 1.0f, 2);
}